// Round 6
// baseline (154.324 us; speedup 1.0000x reference)
//
#include <hip/hip_runtime.h>

#define NROWS 2048
#define KDIM  768
#define L     40
#define HN    (NROWS * L)   // 81920 floats per h matrix

// ---------------------------------------------------------------------------
// Kernel 1: FULL-K projection, one pass, no partials / no k_red.
//   hxb[row][o] = b1[o] + sum_k x[row][k]*W1[o][k]        (which==0)
//   hy [row][o] =         sum_k y[row][k]*W1[o][768+k]    (which==1)
// grid (128 rowblocks, 2 matrices) = 256 blocks (1/CU), 256 thr = 16r x 16seg.
// Per thread: A row slice (12 float4 = 48 regs) loaded ONCE, reused for all
// 40 o; per o: 12 W float4 (256B unique/instr -> 4cyc L1); per-CU L1 cycles
// ~= 4 waves * 480 instr * 4 cyc = 7680 cyc ~= 3.2 us.
// Seg-reduction via proven LDS transpose pattern (stride 688, o*17).
// ---------------------------------------------------------------------------
__global__ __launch_bounds__(256) void k_proj(const float* __restrict__ x,
                                              const float* __restrict__ y,
                                              const float* __restrict__ W1,
                                              const float* __restrict__ b1,
                                              float* __restrict__ hxb,
                                              float* __restrict__ hy) {
    const int which = blockIdx.y;
    const float* __restrict__ A = which ? y : x;
    const int tid = threadIdx.x;
    const int r   = tid >> 4;    // 0..15 row within block
    const int seg = tid & 15;    // 0..15 K-segment
    const int row0 = blockIdx.x * 16;

    __shared__ float sh[16 * 688];

    // A row slice: per kc-chunk of 128, two float4 at seg*4 and 64+seg*4
    const float* arow = A + (size_t)(row0 + r) * KDIM;
    float4 a[12];
#pragma unroll
    for (int kc = 0; kc < 6; ++kc) {
        a[2 * kc]     = *(const float4*)(arow + kc * 128 + seg * 4);
        a[2 * kc + 1] = *(const float4*)(arow + kc * 128 + 64 + seg * 4);
    }

    const float* wbase = W1 + (size_t)which * KDIM;
#pragma unroll 4
    for (int o = 0; o < L; ++o) {
        const float* wrow = wbase + (size_t)o * (2 * KDIM);
        float s = 0.f;
#pragma unroll
        for (int kc = 0; kc < 6; ++kc) {
            float4 w0 = *(const float4*)(wrow + kc * 128 + seg * 4);
            float4 w1 = *(const float4*)(wrow + kc * 128 + 64 + seg * 4);
            float4 a0 = a[2 * kc], a1 = a[2 * kc + 1];
            s += a0.x * w0.x + a0.y * w0.y + a0.z * w0.z + a0.w * w0.w
               + a1.x * w1.x + a1.y * w1.y + a1.z * w1.z + a1.w * w1.w;
        }
        sh[r * 688 + o * 17 + seg] = s;
    }
    __syncthreads();

    // reduce 16 segments -> 640 outputs; b1 folded into hxb here
    float* pout = (which ? hy : hxb) + (size_t)row0 * L;
    for (int idx = tid; idx < 16 * L; idx += 256) {
        int rr = idx / L;
        int o  = idx - rr * L;
        float s = 0.f;
        int base = rr * 688 + o * 17;
#pragma unroll
        for (int q = 0; q < 16; ++q) s += sh[base + q];
        if (!which) s += b1[o];
        pout[idx] = s;
    }
}

// ---------------------------------------------------------------------------
// Kernel 2: pairwise sum of exp(T_ij - 1) + diagonal T0 sum.  (R5-verified)
// Tile BI=128 x BJ=64, block 512 = 32(ty) x 16(tx), micro-tile 4x4,
// 2-deep double-buffered LDS fragment pipeline, no atomics.
// ---------------------------------------------------------------------------
#define BI 128
#define BJ 64
#define STRD 44

__global__ __launch_bounds__(512, 4) void k_pair(const float* __restrict__ hxb,
                                                 const float* __restrict__ hy,
                                                 const float* __restrict__ W2,
                                                 const float* __restrict__ b2p,
                                                 float* __restrict__ pairE,
                                                 float* __restrict__ pairT) {
    __shared__ float shy[BI * STRD];
    __shared__ float shx[BJ * STRD];
    __shared__ float sw2[STRD];
    __shared__ float red[16];

    const int tid = threadIdx.x;
    const int i0 = blockIdx.x * BI;
    const int j0 = blockIdx.y * BJ;

    for (int idx = tid; idx < BI * 10; idx += 512) {
        int rr = idx / 10, c = idx - rr * 10;
        float4 v = ((const float4*)(hy + (size_t)i0 * L))[idx];
        *(float4*)(shy + rr * STRD + c * 4) = v;
    }
    for (int idx = tid; idx < BJ * 10; idx += 512) {
        int rr = idx / 10, c = idx - rr * 10;
        float4 v = ((const float4*)(hxb + (size_t)j0 * L))[idx];
        *(float4*)(shx + rr * STRD + c * 4) = v;
    }
    if (tid < 10) ((float4*)sw2)[tid] = ((const float4*)W2)[tid];
    __syncthreads();

    const int tx = tid & 15, ty = tid >> 4;   // ty 0..31

    float acc[4][4];
#pragma unroll
    for (int u = 0; u < 4; ++u)
#pragma unroll
        for (int v = 0; v < 4; ++v) acc[u][v] = 0.f;

    float4 ayA[4], axA[4], wA4;
    float4 ayB[4], axB[4], wB4;

#define LOADF(AY, AX, W4, K4) do {                                          \
    W4 = *(const float4*)(sw2 + (K4) * 4);                                  \
    _Pragma("unroll") for (int u_ = 0; u_ < 4; ++u_)                        \
        AY[u_] = *(const float4*)(shy + (ty + 32 * u_) * STRD + (K4) * 4);  \
    _Pragma("unroll") for (int v_ = 0; v_ < 4; ++v_)                        \
        AX[v_] = *(const float4*)(shx + (tx + 16 * v_) * STRD + (K4) * 4);  \
} while (0)

#define FMAF(AY, AX, W4) do {                                               \
    _Pragma("unroll") for (int u_ = 0; u_ < 4; ++u_)                        \
    _Pragma("unroll") for (int v_ = 0; v_ < 4; ++v_) {                      \
        float t;                                                            \
        t = AY[u_].x + AX[v_].x; t = fmaxf(t, 0.f); acc[u_][v_] += t * W4.x;\
        t = AY[u_].y + AX[v_].y; t = fmaxf(t, 0.f); acc[u_][v_] += t * W4.y;\
        t = AY[u_].z + AX[v_].z; t = fmaxf(t, 0.f); acc[u_][v_] += t * W4.z;\
        t = AY[u_].w + AX[v_].w; t = fmaxf(t, 0.f); acc[u_][v_] += t * W4.w;\
    }                                                                       \
} while (0)

    LOADF(ayA, axA, wA4, 0);
    LOADF(ayB, axB, wB4, 1);
    FMAF(ayA, axA, wA4); LOADF(ayA, axA, wA4, 2);
    FMAF(ayB, axB, wB4); LOADF(ayB, axB, wB4, 3);
    FMAF(ayA, axA, wA4); LOADF(ayA, axA, wA4, 4);
    FMAF(ayB, axB, wB4); LOADF(ayB, axB, wB4, 5);
    FMAF(ayA, axA, wA4); LOADF(ayA, axA, wA4, 6);
    FMAF(ayB, axB, wB4); LOADF(ayB, axB, wB4, 7);
    FMAF(ayA, axA, wA4); LOADF(ayA, axA, wA4, 8);
    FMAF(ayB, axB, wB4); LOADF(ayB, axB, wB4, 9);
    FMAF(ayA, axA, wA4);
    FMAF(ayB, axB, wB4);

#undef LOADF
#undef FMAF

    const float b2v = b2p[0];
    const float c1  = b2v - 1.f;
    float sumE = 0.f, sumT = 0.f;
#pragma unroll
    for (int u = 0; u < 4; ++u)
#pragma unroll
        for (int v = 0; v < 4; ++v) {
            int gi = i0 + ty + 32 * u;
            int gj = j0 + tx + 16 * v;
            float val = acc[u][v];
            if (gi == gj) sumT += val + b2v;
            sumE += __expf(val + c1);
        }

#pragma unroll
    for (int off = 32; off > 0; off >>= 1) {
        sumE += __shfl_down(sumE, off);
        sumT += __shfl_down(sumT, off);
    }
    int wid = tid >> 6;                     // 0..7
    if ((tid & 63) == 0) { red[wid] = sumE; red[8 + wid] = sumT; }
    __syncthreads();
    if (tid == 0) {
        float e = 0.f, t = 0.f;
#pragma unroll
        for (int q = 0; q < 8; ++q) { e += red[q]; t += red[8 + q]; }
        int bid = blockIdx.y * gridDim.x + blockIdx.x;   // 0..511
        pairE[bid] = e;
        pairT[bid] = t;
    }
}

// ---------------------------------------------------------------------------
// Kernel 3: reduce 512 block-partials -> lower_bound.  (R5-verified)
// ---------------------------------------------------------------------------
__global__ __launch_bounds__(512) void k_fin(const float* __restrict__ pairE,
                                             const float* __restrict__ pairT,
                                             float* __restrict__ out) {
    __shared__ float red[16];
    const int tid = threadIdx.x;
    float e = pairE[tid];
    float t = pairT[tid];
#pragma unroll
    for (int off = 32; off > 0; off >>= 1) {
        e += __shfl_down(e, off);
        t += __shfl_down(t, off);
    }
    int wid = tid >> 6;
    if ((tid & 63) == 0) { red[wid] = e; red[8 + wid] = t; }
    __syncthreads();
    if (tid == 0) {
        float se = 0.f, st = 0.f;
#pragma unroll
        for (int q = 0; q < 8; ++q) { se += red[q]; st += red[8 + q]; }
        const float invN = 1.0f / (float)NROWS;
        out[0] = st * invN - se * invN * invN;
    }
}

extern "C" void kernel_launch(void* const* d_in, const int* in_sizes, int n_in,
                              void* d_out, int out_size, void* d_ws, size_t ws_size,
                              hipStream_t stream) {
    const float* x  = (const float*)d_in[0];
    const float* y  = (const float*)d_in[1];
    const float* W1 = (const float*)d_in[2];
    const float* b1 = (const float*)d_in[3];
    const float* W2 = (const float*)d_in[4];
    const float* b2 = (const float*)d_in[5];
    float* out = (float*)d_out;

    float* wsf   = (float*)d_ws;
    float* hxb   = wsf;                  // 2048*40, b1 folded in
    float* hy    = hxb + HN;             // 2048*40
    float* pairE = hy + HN;              // 512
    float* pairT = pairE + 512;          // 512

    k_proj<<<dim3(NROWS / 16, 2), 256, 0, stream>>>(x, y, W1, b1, hxb, hy);
    k_pair<<<dim3(NROWS / BI, NROWS / BJ), 512, 0, stream>>>(hxb, hy, W2, b2, pairE, pairT);
    k_fin<<<1, 512, 0, stream>>>(pairE, pairT, out);
}

// Round 7
// 97.153 us; speedup vs baseline: 1.5885x; 1.5885x over previous
//
#include <hip/hip_runtime.h>

#define NROWS 2048
#define KDIM  768
#define L     40
#define HN    (NROWS * L)   // 81920 floats per h matrix

// ---------------------------------------------------------------------------
// Kernel 1: full-K projection, shfl-reduced, o-split for occupancy.
//   hxb[row][o] = b1[o] + sum_k x[row][k]*W1[o][k]        (which==0)
//   hy [row][o] =         sum_k y[row][k]*W1[o][768+k]    (which==1)
// grid (256 rowblocks, 2 which, 2 o-halves) = 1024 blocks, 256 thr
//   = 8 rows x 32 segs  ->  4 blocks/CU = 16 waves/CU = 4 waves/SIMD.
// (R6 lesson: full-K at 256 blocks was 1 wave/SIMD -> 99us pure latency.)
// Per thread: 6 a-float4 held in regs; per o: 6 W float4 (wave-broadcast:
// both 32-lane row-groups read identical W addresses -> one 512B fetch).
// Dot-reduce across 32 segs via 5x shfl_xor -- no LDS tile, no k_red.
// ---------------------------------------------------------------------------
__global__ __launch_bounds__(256) void k_proj(const float* __restrict__ x,
                                              const float* __restrict__ y,
                                              const float* __restrict__ W1,
                                              const float* __restrict__ b1,
                                              float* __restrict__ hxb,
                                              float* __restrict__ hy) {
    const int which = blockIdx.y;
    const int oh    = blockIdx.z;          // o-half: 0 -> o 0..19, 1 -> o 20..39
    const float* __restrict__ A = which ? y : x;
    const int tid = threadIdx.x;
    const int r   = tid >> 5;              // 0..7 row within block
    const int seg = tid & 31;              // 0..31 K-segment (4 floats x 6 chunks)
    const int row0 = blockIdx.x * 8;

    __shared__ float sh2[8 * 21];          // [8 rows][20 o (+1 pad)]

    const float* arow = A + (size_t)(row0 + r) * KDIM;
    float4 a[6];
#pragma unroll
    for (int q = 0; q < 6; ++q)
        a[q] = *(const float4*)(arow + q * 128 + seg * 4);

    const float* wbase = W1 + (size_t)which * KDIM + (size_t)(oh * 20) * (2 * KDIM);
#pragma unroll 2
    for (int ol = 0; ol < 20; ++ol) {
        const float* wrow = wbase + (size_t)ol * (2 * KDIM);
        float s = 0.f;
#pragma unroll
        for (int q = 0; q < 6; ++q) {
            float4 w = *(const float4*)(wrow + q * 128 + seg * 4);
            s += a[q].x * w.x + a[q].y * w.y + a[q].z * w.z + a[q].w * w.w;
        }
        // reduce across the 32 segs (stays within each 32-lane half of the wave)
        s += __shfl_xor(s, 16);
        s += __shfl_xor(s, 8);
        s += __shfl_xor(s, 4);
        s += __shfl_xor(s, 2);
        s += __shfl_xor(s, 1);
        if (seg == 0) sh2[r * 21 + ol] = s;
    }
    __syncthreads();

    if (tid < 8 * 20) {
        int rr = tid / 20, ol = tid - rr * 20;
        float s = sh2[rr * 21 + ol];
        int o = oh * 20 + ol;
        if (!which) {
            s += b1[o];
            hxb[(size_t)(row0 + rr) * L + o] = s;
        } else {
            hy[(size_t)(row0 + rr) * L + o] = s;
        }
    }
}

// ---------------------------------------------------------------------------
// Kernel 2: pairwise sum of exp(T_ij - 1) + diagonal T0 sum.  (R5-verified,
// measured ~9us in R6 budget fit -- leave untouched.)
// Tile BI=128 x BJ=64, block 512 = 32(ty) x 16(tx), micro-tile 4x4,
// 2-deep double-buffered LDS fragment pipeline, no atomics.
// ---------------------------------------------------------------------------
#define BI 128
#define BJ 64
#define STRD 44

__global__ __launch_bounds__(512, 4) void k_pair(const float* __restrict__ hxb,
                                                 const float* __restrict__ hy,
                                                 const float* __restrict__ W2,
                                                 const float* __restrict__ b2p,
                                                 float* __restrict__ pairE,
                                                 float* __restrict__ pairT) {
    __shared__ float shy[BI * STRD];
    __shared__ float shx[BJ * STRD];
    __shared__ float sw2[STRD];
    __shared__ float red[16];

    const int tid = threadIdx.x;
    const int i0 = blockIdx.x * BI;
    const int j0 = blockIdx.y * BJ;

    for (int idx = tid; idx < BI * 10; idx += 512) {
        int rr = idx / 10, c = idx - rr * 10;
        float4 v = ((const float4*)(hy + (size_t)i0 * L))[idx];
        *(float4*)(shy + rr * STRD + c * 4) = v;
    }
    for (int idx = tid; idx < BJ * 10; idx += 512) {
        int rr = idx / 10, c = idx - rr * 10;
        float4 v = ((const float4*)(hxb + (size_t)j0 * L))[idx];
        *(float4*)(shx + rr * STRD + c * 4) = v;
    }
    if (tid < 10) ((float4*)sw2)[tid] = ((const float4*)W2)[tid];
    __syncthreads();

    const int tx = tid & 15, ty = tid >> 4;   // ty 0..31

    float acc[4][4];
#pragma unroll
    for (int u = 0; u < 4; ++u)
#pragma unroll
        for (int v = 0; v < 4; ++v) acc[u][v] = 0.f;

    float4 ayA[4], axA[4], wA4;
    float4 ayB[4], axB[4], wB4;

#define LOADF(AY, AX, W4, K4) do {                                          \
    W4 = *(const float4*)(sw2 + (K4) * 4);                                  \
    _Pragma("unroll") for (int u_ = 0; u_ < 4; ++u_)                        \
        AY[u_] = *(const float4*)(shy + (ty + 32 * u_) * STRD + (K4) * 4);  \
    _Pragma("unroll") for (int v_ = 0; v_ < 4; ++v_)                        \
        AX[v_] = *(const float4*)(shx + (tx + 16 * v_) * STRD + (K4) * 4);  \
} while (0)

#define FMAF(AY, AX, W4) do {                                               \
    _Pragma("unroll") for (int u_ = 0; u_ < 4; ++u_)                        \
    _Pragma("unroll") for (int v_ = 0; v_ < 4; ++v_) {                      \
        float t;                                                            \
        t = AY[u_].x + AX[v_].x; t = fmaxf(t, 0.f); acc[u_][v_] += t * W4.x;\
        t = AY[u_].y + AX[v_].y; t = fmaxf(t, 0.f); acc[u_][v_] += t * W4.y;\
        t = AY[u_].z + AX[v_].z; t = fmaxf(t, 0.f); acc[u_][v_] += t * W4.z;\
        t = AY[u_].w + AX[v_].w; t = fmaxf(t, 0.f); acc[u_][v_] += t * W4.w;\
    }                                                                       \
} while (0)

    LOADF(ayA, axA, wA4, 0);
    LOADF(ayB, axB, wB4, 1);
    FMAF(ayA, axA, wA4); LOADF(ayA, axA, wA4, 2);
    FMAF(ayB, axB, wB4); LOADF(ayB, axB, wB4, 3);
    FMAF(ayA, axA, wA4); LOADF(ayA, axA, wA4, 4);
    FMAF(ayB, axB, wB4); LOADF(ayB, axB, wB4, 5);
    FMAF(ayA, axA, wA4); LOADF(ayA, axA, wA4, 6);
    FMAF(ayB, axB, wB4); LOADF(ayB, axB, wB4, 7);
    FMAF(ayA, axA, wA4); LOADF(ayA, axA, wA4, 8);
    FMAF(ayB, axB, wB4); LOADF(ayB, axB, wB4, 9);
    FMAF(ayA, axA, wA4);
    FMAF(ayB, axB, wB4);

#undef LOADF
#undef FMAF

    const float b2v = b2p[0];
    const float c1  = b2v - 1.f;
    float sumE = 0.f, sumT = 0.f;
#pragma unroll
    for (int u = 0; u < 4; ++u)
#pragma unroll
        for (int v = 0; v < 4; ++v) {
            int gi = i0 + ty + 32 * u;
            int gj = j0 + tx + 16 * v;
            float val = acc[u][v];
            if (gi == gj) sumT += val + b2v;
            sumE += __expf(val + c1);
        }

#pragma unroll
    for (int off = 32; off > 0; off >>= 1) {
        sumE += __shfl_down(sumE, off);
        sumT += __shfl_down(sumT, off);
    }
    int wid = tid >> 6;                     // 0..7
    if ((tid & 63) == 0) { red[wid] = sumE; red[8 + wid] = sumT; }
    __syncthreads();
    if (tid == 0) {
        float e = 0.f, t = 0.f;
#pragma unroll
        for (int q = 0; q < 8; ++q) { e += red[q]; t += red[8 + q]; }
        int bid = blockIdx.y * gridDim.x + blockIdx.x;   // 0..511
        pairE[bid] = e;
        pairT[bid] = t;
    }
}

// ---------------------------------------------------------------------------
// Kernel 3: reduce 512 block-partials -> lower_bound.  (R5-verified)
// ---------------------------------------------------------------------------
__global__ __launch_bounds__(512) void k_fin(const float* __restrict__ pairE,
                                             const float* __restrict__ pairT,
                                             float* __restrict__ out) {
    __shared__ float red[16];
    const int tid = threadIdx.x;
    float e = pairE[tid];
    float t = pairT[tid];
#pragma unroll
    for (int off = 32; off > 0; off >>= 1) {
        e += __shfl_down(e, off);
        t += __shfl_down(t, off);
    }
    int wid = tid >> 6;
    if ((tid & 63) == 0) { red[wid] = e; red[8 + wid] = t; }
    __syncthreads();
    if (tid == 0) {
        float se = 0.f, st = 0.f;
#pragma unroll
        for (int q = 0; q < 8; ++q) { se += red[q]; st += red[8 + q]; }
        const float invN = 1.0f / (float)NROWS;
        out[0] = st * invN - se * invN * invN;
    }
}

extern "C" void kernel_launch(void* const* d_in, const int* in_sizes, int n_in,
                              void* d_out, int out_size, void* d_ws, size_t ws_size,
                              hipStream_t stream) {
    const float* x  = (const float*)d_in[0];
    const float* y  = (const float*)d_in[1];
    const float* W1 = (const float*)d_in[2];
    const float* b1 = (const float*)d_in[3];
    const float* W2 = (const float*)d_in[4];
    const float* b2 = (const float*)d_in[5];
    float* out = (float*)d_out;

    float* wsf   = (float*)d_ws;
    float* hxb   = wsf;                  // 2048*40, b1 folded in
    float* hy    = hxb + HN;             // 2048*40
    float* pairE = hy + HN;              // 512
    float* pairT = pairE + 512;          // 512

    k_proj<<<dim3(NROWS / 8, 2, 2), 256, 0, stream>>>(x, y, W1, b1, hxb, hy);
    k_pair<<<dim3(NROWS / BI, NROWS / BJ), 512, 0, stream>>>(hxb, hy, W2, b2, pairE, pairT);
    k_fin<<<1, 512, 0, stream>>>(pairE, pairT, out);
}